// Round 8
// baseline (94.187 us; speedup 1.0000x reference)
//
#include <hip/hip_runtime.h>
#include <math.h>

#define RESN 2048
#define TEXW 1024

// atan2 for y >= 0, returns [0, pi]. Cephes-style: min/max ratio + pi/8
// reduction + 4-term odd minimax + 1 Newton step on rcp. Peak err ~3e-7 rad.
__device__ __forceinline__ float fatan2_pos(float y, float x) {
    float ax = fabsf(x);
    float mn = fminf(ax, y);
    float mx = fmaxf(ax, y);
    float r0 = __builtin_amdgcn_rcpf(mx);
    r0 = r0 * __builtin_fmaf(-mx, r0, 2.0f);        // 1 Newton step -> ~0.5 ulp
    float a = mn * r0;                               // in [0,1]
    bool red = a > 0.41421356f;
    float t = (a - 1.0f) * __builtin_amdgcn_rcpf(a + 1.0f);
    float w = red ? t : a;                           // |w| <= 0.41421356
    float s = w * w;
    float p = __builtin_fmaf(s, 8.05374449538e-2f, -1.38776856032e-1f);
    p = __builtin_fmaf(s, p, 1.99777106478e-1f);
    p = __builtin_fmaf(s, p, -3.33329491539e-1f);
    float r = __builtin_fmaf(w * s, p, w);           // atan(w)
    r = red ? r + 0.78539816339f : r;                // + pi/4
    r = (y > ax) ? 1.57079632679f - r : r;
    r = (x < 0.0f) ? 3.14159265359f - r : r;
    return r;
}

// 12-byte texel -> global_load_dwordx3
struct __align__(4) F3 { float x, y, z; };

__global__ __launch_bounds__(256, 8) void egg_render(
    const float* __restrict__ tex,
    const float* __restrict__ nmap,
    float* __restrict__ out)
{
    // 2 px/thread, same row, 64 apart: row math shared, two independent
    // gather+shade streams give 2x ILP while VGPR stays <=64 (8 waves/SIMD).
    int t = blockIdx.x * 256 + threadIdx.x;          // 2,097,152 threads
    int j = t >> 10;                                  // row
    int tr = t & 1023;
    int seg = tr >> 6;                                // 16 segments of 128 px
    int lane = tr & 63;
    int iA = (seg << 7) + lane;                       // first half of segment
    int iB = iA + 64;                                 // second half
    float* oA = out + ((size_t)j * RESN + iA) * 3u;
    float* oB = oA + 192u;                            // +64 px

    const float invres = 1.0f / (float)RESN;
    // bit-exact vs numpy on the inside-test path: no fma contraction
    float ny = __fmul_rn(__fsub_rn(0.5f, __fmul_rn((float)j, invres)), 2.0f) / 0.85f;
    float nysq = __fmul_rn(ny, ny);

    if (!(nysq <= 1.0f)) {                            // whole row outside
        oA[0] = 0.f; oA[1] = 0.f; oA[2] = 0.f;
        oB[0] = 0.f; oB[1] = 0.f; oB[2] = 0.f;
        return;
    }

    // ---- row-shared (ny-only) ----
    float egg = 1.0f - 0.25f * ny;                    // in [0.75, 1.25]
    float sphi = sqrtf(fmaxf(__builtin_fmaf(-ny, ny, 1.0f), 0.0f));
    float phi = fatan2_pos(sphi, ny);                 // == acos(ny)
    float v = phi * 0.3183098861837907f;              // /pi
    v -= floorf(v);
    float yy = v * (float)TEXW - 0.5f;
    float yf = floorf(yy);
    float fy = yy - yf;
    float gy = 1.0f - fy;
    int y0 = (int)yf & (TEXW - 1);
    int y1 = (y0 + 1) & (TEXW - 1);
    int rb0 = y0 * TEXW;
    int rb1 = y1 * TEXW;

    // ---- per-pixel phase 1: uv + issue 8 loads ----
    struct Px {
        float nx, z, w00, w01, w10, w11;
        bool inside;
        F3 a00, a01, a10, a11, n00, n01, n10, n11;
    };

    auto phase1 = [&](int i, Px& P) {
        float nx = __fmul_rn(__fsub_rn(__fmul_rn((float)i, invres), 0.5f), 2.0f) / 0.85f;
        float rsq = __fadd_rn(__fmul_rn(nx, nx), nysq);
        P.inside = (rsq <= 1.0f);
        if (!P.inside) return;
        float z = sqrtf(fmaxf(__fsub_rn(1.0f, rsq), 0.0f));
        P.nx = nx; P.z = z;
        // atan2(z/egg, nx/egg) == atan2(z, nx): egg > 0 inside the disc
        float theta = fatan2_pos(z, nx);
        float u = theta * 0.15915494309189535f + 0.5f;    // /(2pi)
        u -= floorf(u);
        float xx = u * (float)TEXW - 0.5f;
        float xf = floorf(xx);
        float fx = xx - xf;
        float gx = 1.0f - fx;
        int x0 = (int)xf & (TEXW - 1);
        int x1 = (x0 + 1) & (TEXW - 1);
        P.w00 = gx * gy; P.w01 = fx * gy; P.w10 = gx * fy; P.w11 = fx * fy;
        int o00 = (rb0 + x0) * 3;
        int o01 = (rb0 + x1) * 3;
        int o10 = (rb1 + x0) * 3;
        int o11 = (rb1 + x1) * 3;
        P.a00 = *(const F3*)(tex + o00);
        P.a01 = *(const F3*)(tex + o01);
        P.a10 = *(const F3*)(tex + o10);
        P.a11 = *(const F3*)(tex + o11);
        P.n00 = *(const F3*)(nmap + o00);
        P.n01 = *(const F3*)(nmap + o01);
        P.n10 = *(const F3*)(nmap + o10);
        P.n11 = *(const F3*)(nmap + o11);
    };

    // ---- per-pixel phase 2: blend + shade + store ----
    auto phase2 = [&](const Px& P, float* o) {
        if (!P.inside) { o[0] = 0.f; o[1] = 0.f; o[2] = 0.f; return; }
        float w00 = P.w00, w01 = P.w01, w10 = P.w10, w11 = P.w11;
        float ar = P.a00.x*w00 + P.a01.x*w01 + P.a10.x*w10 + P.a11.x*w11;
        float ag = P.a00.y*w00 + P.a01.y*w01 + P.a10.y*w10 + P.a11.y*w11;
        float ab = P.a00.z*w00 + P.a01.z*w01 + P.a10.z*w10 + P.a11.z*w11;
        float tnx = (P.n00.x*w00 + P.n01.x*w01 + P.n10.x*w10 + P.n11.x*w11) * 2.0f - 1.0f;
        float tny = (P.n00.y*w00 + P.n01.y*w01 + P.n10.y*w10 + P.n11.y*w11) * 2.0f - 1.0f;
        float tnz = (P.n00.z*w00 + P.n01.z*w01 + P.n10.z*w10 + P.n11.z*w11) * 2.0f - 1.0f;

        // analytical egg normal (|sn|^2 >= 0.5625 inside the disc)
        float snx = P.nx * egg, sny = ny, snz = P.z * egg;
        float sl2 = snx*snx + sny*sny + snz*snz;
        float isl = __builtin_amdgcn_rsqf(sl2);
        float bnx = snx * isl, bny = sny * isl, bnz = snz * isl;

        // Gram-Schmidt TBN (|t|^2 >= 0.0199)
        bool use_right = fabsf(bny) > 0.99f;
        float rx = use_right ? 1.0f : 0.0f;
        float ry = use_right ? 0.0f : 1.0f;
        float d  = use_right ? bnx : bny;
        float tx = rx - d * bnx;
        float ty = ry - d * bny;
        float tz = -d * bnz;
        float tl2 = tx*tx + ty*ty + tz*tz;
        float itl = __builtin_amdgcn_rsqf(tl2);
        tx *= itl; ty *= itl; tz *= itl;
        float bxx = bny * tz - bnz * ty;
        float bxy = bnz * tx - bnx * tz;
        float bxz = bnx * ty - bny * tx;

        // perturbed normal; BUMP_STRENGTH = 1 -> nrm = normalize(world_n)
        float wx = tnx * tx + tny * bxx + tnz * bnx;
        float wy = tnx * ty + tny * bxy + tnz * bny;
        float wz = tnx * tz + tny * bxz + tnz * bnz;
        float wl2 = wx*wx + wy*wy + wz*wz;
        float iwl = __builtin_amdgcn_rsqf(fmaxf(wl2, 1e-12f));
        wx *= iwl; wy *= iwl; wz *= iwl;

        // lighting constants (compile-time folded, f32 semantics)
        float Lx = 0.5f, Ly = 0.7f, Lz = 1.0f;
        float ll = sqrtf(Lx * Lx + Ly * Ly + Lz * Lz);
        Lx /= ll; Ly /= ll; Lz /= ll;
        float Hx = Lx, Hy = Ly, Hz = Lz + 1.0f;
        float hl = sqrtf(Hx * Hx + Hy * Hy + Hz * Hz);
        Hx /= hl; Hy /= hl; Hz /= hl;

        float ndotl = fmaxf(wx * Lx + wy * Ly + wz * Lz, 0.0f);
        float ndoth = fmaxf(wx * Hx + wy * Hy + wz * Hz, 0.0f);
        float s2 = ndoth * ndoth, s4 = s2 * s2, s8 = s4 * s4, s16 = s8 * s8;
        float spec = s16 * s16;                   // ndoth^32
        float ndotv = fmaxf(wz, 0.0f);
        float t1 = 1.0f - ndotv;
        float t2 = t1 * t1, t4 = t2 * t2;
        float fres = 0.04f + 0.96f * (t4 * t1);   // Schlick, F0=0.04
        float ka = 0.1f + ndotl;
        float add = spec * fres;

        o[0] = fminf(fmaxf(__builtin_fmaf(ar, ka, add), 0.0f), 1.0f);
        o[1] = fminf(fmaxf(__builtin_fmaf(ag, ka, add), 0.0f), 1.0f);
        o[2] = fminf(fmaxf(__builtin_fmaf(ab, ka, add), 0.0f), 1.0f);
    };

    Px A, B;
    phase1(iA, A);      // issue A's 8 loads
    phase1(iB, B);      // issue B's 8 loads (independent of A's results)
    phase2(A, oA);      // A's blend waits only on A's loads; B's in flight
    phase2(B, oB);
}

extern "C" void kernel_launch(void* const* d_in, const int* in_sizes, int n_in,
                              void* d_out, int out_size, void* d_ws, size_t ws_size,
                              hipStream_t stream) {
    const float* tex  = (const float*)d_in[0];
    const float* nmap = (const float*)d_in[1];
    float* out = (float*)d_out;
    int total_threads = RESN * RESN / 2;          // 2,097,152
    dim3 grid(total_threads / 256), block(256);   // 8192 blocks
    hipLaunchKernelGGL(egg_render, grid, block, 0, stream, tex, nmap, out);
}

// Round 9
// 32.086 us; speedup vs baseline: 2.9355x; 2.9355x over previous
//
#include <hip/hip_runtime.h>
#include <math.h>

#define RESN 2048
#define TEXW 1024

// atan2 for y >= 0, returns [0, pi]. Cephes-style: min/max ratio + pi/8
// reduction + 4-term odd minimax + 1 Newton step on rcp. Peak err ~3e-7 rad.
__device__ __forceinline__ float fatan2_pos(float y, float x) {
    float ax = fabsf(x);
    float mn = fminf(ax, y);
    float mx = fmaxf(ax, y);
    float r0 = __builtin_amdgcn_rcpf(mx);
    r0 = r0 * __builtin_fmaf(-mx, r0, 2.0f);        // 1 Newton step -> ~0.5 ulp
    float a = mn * r0;                               // in [0,1]
    bool red = a > 0.41421356f;
    float t = (a - 1.0f) * __builtin_amdgcn_rcpf(a + 1.0f);
    float w = red ? t : a;                           // |w| <= 0.41421356
    float s = w * w;
    float p = __builtin_fmaf(s, 8.05374449538e-2f, -1.38776856032e-1f);
    p = __builtin_fmaf(s, p, 1.99777106478e-1f);
    p = __builtin_fmaf(s, p, -3.33329491539e-1f);
    float r = __builtin_fmaf(w * s, p, w);           // atan(w)
    r = red ? r + 0.78539816339f : r;                // + pi/4
    r = (y > ax) ? 1.57079632679f - r : r;
    r = (x < 0.0f) ? 3.14159265359f - r : r;
    return r;
}

// 12-byte texel -> global_load_dwordx3
struct __align__(4) F3 { float x, y, z; };

// per-row memoized constants (32B, one cache line for the wave's uniform load)
struct __align__(16) RowRec {
    float ny, nysq, egg, fy;
    float gy; int rb0, rb1, pad;
};

// tiny pre-pass: memoize all row-uniform (and column) math with the exact
// same fp op sequence as before -> main-kernel outputs bit-identical.
__global__ __launch_bounds__(256) void build_tables(float* __restrict__ colX,
                                                    RowRec* __restrict__ rows) {
    int idx = blockIdx.x * 256 + threadIdx.x;
    if (idx >= RESN) return;
    const float invres = 1.0f / (float)RESN;
    // column table: nx (bit-exact chain, no fma contraction)
    float nx = __fmul_rn(__fsub_rn(__fmul_rn((float)idx, invres), 0.5f), 2.0f) / 0.85f;
    colX[idx] = nx;
    // row record
    float ny = __fmul_rn(__fsub_rn(0.5f, __fmul_rn((float)idx, invres)), 2.0f) / 0.85f;
    RowRec r;
    r.ny = ny;
    r.nysq = __fmul_rn(ny, ny);
    r.egg = 1.0f - 0.25f * ny;
    float sphi = sqrtf(fmaxf(__builtin_fmaf(-ny, ny, 1.0f), 0.0f));
    float phi = fatan2_pos(sphi, ny);                // == acos(ny)
    float v = phi * 0.3183098861837907f;             // /pi
    v -= floorf(v);
    float yy = v * (float)TEXW - 0.5f;
    float yf = floorf(yy);
    r.fy = yy - yf;
    r.gy = 1.0f - r.fy;
    int y0 = (int)yf & (TEXW - 1);
    int y1 = (y0 + 1) & (TEXW - 1);
    r.rb0 = y0 * TEXW;
    r.rb1 = y1 * TEXW;
    r.pad = 0;
    rows[idx] = r;
}

__global__ __launch_bounds__(256, 8) void egg_render(
    const float* __restrict__ tex,
    const float* __restrict__ nmap,
    const float* __restrict__ colX,
    const RowRec* __restrict__ rows,
    float* __restrict__ out)
{
    // 1 px/thread (best measured structure): lanes 1 px apart, stores are
    // 768B contiguous full-line bursts per wave (WRITE_SIZE stays 50MB).
    int p = blockIdx.x * 256 + threadIdx.x;
    int i = p & (RESN - 1);
    int j = p >> 11;
    float* o = out + (size_t)p * 3u;

    // wave-uniform row record: one 64B line, broadcast to all lanes
    RowRec R = rows[j];
    float nx = colX[i];                           // coalesced dword

    float rsq = __fadd_rn(__fmul_rn(nx, nx), R.nysq);
    if (!(rsq <= 1.0f)) {
        o[0] = 0.0f; o[1] = 0.0f; o[2] = 0.0f;
        return;
    }

    float z = sqrtf(fmaxf(__fsub_rn(1.0f, rsq), 0.0f));

    // atan2(z/egg, nx/egg) == atan2(z, nx): egg > 0 inside the disc
    float theta = fatan2_pos(z, nx);
    float u = theta * 0.15915494309189535f + 0.5f;   // /(2pi)
    u -= floorf(u);

    // x-side bilinear (y-side from row table)
    float xx = u * (float)TEXW - 0.5f;
    float xf = floorf(xx);
    float fx = xx - xf;
    float gx = 1.0f - fx;
    int x0 = (int)xf & (TEXW - 1);
    int x1 = (x0 + 1) & (TEXW - 1);
    float w00 = gx * R.gy, w01 = fx * R.gy, w10 = gx * R.fy, w11 = fx * R.fy;
    int o00 = (R.rb0 + x0) * 3;
    int o01 = (R.rb0 + x1) * 3;
    int o10 = (R.rb1 + x0) * 3;
    int o11 = (R.rb1 + x1) * 3;

    F3 a00 = *(const F3*)(tex + o00);
    F3 a01 = *(const F3*)(tex + o01);
    F3 a10 = *(const F3*)(tex + o10);
    F3 a11 = *(const F3*)(tex + o11);
    F3 n00 = *(const F3*)(nmap + o00);
    F3 n01 = *(const F3*)(nmap + o01);
    F3 n10 = *(const F3*)(nmap + o10);
    F3 n11 = *(const F3*)(nmap + o11);

    float ar = a00.x*w00 + a01.x*w01 + a10.x*w10 + a11.x*w11;
    float ag = a00.y*w00 + a01.y*w01 + a10.y*w10 + a11.y*w11;
    float ab = a00.z*w00 + a01.z*w01 + a10.z*w10 + a11.z*w11;
    float tnx = (n00.x*w00 + n01.x*w01 + n10.x*w10 + n11.x*w11) * 2.0f - 1.0f;
    float tny = (n00.y*w00 + n01.y*w01 + n10.y*w10 + n11.y*w11) * 2.0f - 1.0f;
    float tnz = (n00.z*w00 + n01.z*w01 + n10.z*w10 + n11.z*w11) * 2.0f - 1.0f;

    // analytical egg normal (|sn|^2 >= 0.5625 inside the disc)
    float ny = R.ny, egg = R.egg;
    float snx = nx * egg, sny = ny, snz = z * egg;
    float sl2 = snx*snx + sny*sny + snz*snz;
    float isl = __builtin_amdgcn_rsqf(sl2);
    float bnx = snx * isl, bny = sny * isl, bnz = snz * isl;

    // Gram-Schmidt TBN (|t|^2 >= 0.0199)
    bool use_right = fabsf(bny) > 0.99f;
    float rx = use_right ? 1.0f : 0.0f;
    float ry = use_right ? 0.0f : 1.0f;
    float d  = use_right ? bnx : bny;
    float tx = rx - d * bnx;
    float ty = ry - d * bny;
    float tz = -d * bnz;
    float tl2 = tx*tx + ty*ty + tz*tz;
    float itl = __builtin_amdgcn_rsqf(tl2);
    tx *= itl; ty *= itl; tz *= itl;
    float bxx = bny * tz - bnz * ty;
    float bxy = bnz * tx - bnx * tz;
    float bxz = bnx * ty - bny * tx;

    // perturbed normal; BUMP_STRENGTH = 1 -> nrm = normalize(world_n)
    float wx = tnx * tx + tny * bxx + tnz * bnx;
    float wy = tnx * ty + tny * bxy + tnz * bny;
    float wz = tnx * tz + tny * bxz + tnz * bnz;
    float wl2 = wx*wx + wy*wy + wz*wz;
    float iwl = __builtin_amdgcn_rsqf(fmaxf(wl2, 1e-12f));
    wx *= iwl; wy *= iwl; wz *= iwl;

    // lighting constants (compile-time folded, f32 semantics)
    float Lx = 0.5f, Ly = 0.7f, Lz = 1.0f;
    float ll = sqrtf(Lx * Lx + Ly * Ly + Lz * Lz);
    Lx /= ll; Ly /= ll; Lz /= ll;
    float Hx = Lx, Hy = Ly, Hz = Lz + 1.0f;
    float hl = sqrtf(Hx * Hx + Hy * Hy + Hz * Hz);
    Hx /= hl; Hy /= hl; Hz /= hl;

    float ndotl = fmaxf(wx * Lx + wy * Ly + wz * Lz, 0.0f);
    float ndoth = fmaxf(wx * Hx + wy * Hy + wz * Hz, 0.0f);
    float s2 = ndoth * ndoth, s4 = s2 * s2, s8 = s4 * s4, s16 = s8 * s8;
    float spec = s16 * s16;                   // ndoth^32
    float ndotv = fmaxf(wz, 0.0f);
    float t1 = 1.0f - ndotv;
    float t2 = t1 * t1, t4 = t2 * t2;
    float fres = 0.04f + 0.96f * (t4 * t1);   // Schlick, F0=0.04
    float ka = 0.1f + ndotl;
    float add = spec * fres;

    // 3 adjacent dword stores -> dwordx3; wave covers 768B contiguous burst
    o[0] = fminf(fmaxf(__builtin_fmaf(ar, ka, add), 0.0f), 1.0f);
    o[1] = fminf(fmaxf(__builtin_fmaf(ag, ka, add), 0.0f), 1.0f);
    o[2] = fminf(fmaxf(__builtin_fmaf(ab, ka, add), 0.0f), 1.0f);
}

extern "C" void kernel_launch(void* const* d_in, const int* in_sizes, int n_in,
                              void* d_out, int out_size, void* d_ws, size_t ws_size,
                              hipStream_t stream) {
    const float* tex  = (const float*)d_in[0];
    const float* nmap = (const float*)d_in[1];
    float* out = (float*)d_out;

    // ws layout: [0, 8KB) column nx table; [8KB, 8KB+64KB) row records
    float* colX = (float*)d_ws;
    RowRec* rows = (RowRec*)((char*)d_ws + 8192);

    hipLaunchKernelGGL(build_tables, dim3(RESN / 256), dim3(256), 0, stream,
                       colX, rows);

    int total = RESN * RESN;                      // 1 px/thread
    hipLaunchKernelGGL(egg_render, dim3(total / 256), dim3(256), 0, stream,
                       tex, nmap, colX, rows, out);
}

// Round 10
// 28.451 us; speedup vs baseline: 3.3105x; 1.1278x over previous
//
#include <hip/hip_runtime.h>
#include <math.h>

#define RESN 2048
#define TEXW 1024

// atan2 for y >= 0, returns [0, pi]. Cephes-style: min/max ratio + pi/8
// reduction + 4-term odd minimax + 1 Newton step on rcp. Peak err ~2e-7 rad.
__device__ __forceinline__ float fatan2_pos(float y, float x) {
    float ax = fabsf(x);
    float mn = fminf(ax, y);
    float mx = fmaxf(ax, y);
    float r0 = __builtin_amdgcn_rcpf(mx);
    r0 = r0 * __builtin_fmaf(-mx, r0, 2.0f);        // 1 Newton step -> ~0.5 ulp
    float a = mn * r0;                               // in [0,1]
    bool red = a > 0.41421356f;
    float t = (a - 1.0f) * __builtin_amdgcn_rcpf(a + 1.0f);
    float w = red ? t : a;                           // |w| <= 0.41421356
    float s = w * w;
    float p = __builtin_fmaf(s, 8.05374449538e-2f, -1.38776856032e-1f);
    p = __builtin_fmaf(s, p, 1.99777106478e-1f);
    p = __builtin_fmaf(s, p, -3.33329491539e-1f);
    float r = __builtin_fmaf(w * s, p, w);           // atan(w)
    r = red ? r + 0.78539816339f : r;                // + pi/4
    r = (y > ax) ? 1.57079632679f - r : r;
    r = (x < 0.0f) ? 3.14159265359f - r : r;
    return r;
}

// 12-byte texel -> global_load_dwordx3
struct __align__(4) F3 { float x, y, z; };

__global__ __launch_bounds__(256, 8) void egg_render(
    const float* __restrict__ tex,
    const float* __restrict__ nmap,
    float* __restrict__ out)
{
    // 1 px/thread: lanes 1 px apart (minimal texel span per wave-gather);
    // 12B/lane contiguous stores -> full 64B-line coverage per wave burst.
    int p = blockIdx.x * 256 + threadIdx.x;
    int i = p & (RESN - 1);
    int j = p >> 11;
    float* o = out + (size_t)p * 3u;

    const float invres = 1.0f / (float)RESN;
    // bit-exact vs numpy on the inside-test path: no fma contraction,
    // true IEEE division by 0.85 (rcp-based would risk rim-pixel flips)
    float nx = __fmul_rn(__fsub_rn(__fmul_rn((float)i, invres), 0.5f), 2.0f) / 0.85f;
    float ny = __fmul_rn(__fsub_rn(0.5f, __fmul_rn((float)j, invres)), 2.0f) / 0.85f;
    float rsq = __fadd_rn(__fmul_rn(nx, nx), __fmul_rn(ny, ny));
    if (!(rsq <= 1.0f)) {
        o[0] = 0.0f; o[1] = 0.0f; o[2] = 0.0f;
        return;
    }

    float z = sqrtf(fmaxf(__fsub_rn(1.0f, rsq), 0.0f));
    float egg = 1.0f - 0.25f * ny;               // in [0.75, 1.25] inside the disc

    // phi = acos(ny) via atan2(sqrt(1-ny^2), ny); fma keeps 1-ny^2 single-rounded
    float sphi = sqrtf(fmaxf(__builtin_fmaf(-ny, ny, 1.0f), 0.0f));
    float phi = fatan2_pos(sphi, ny);
    // phi in [0,pi] -> v in [0,1]; v==1.0 endpoint maps to the same
    // (y0,y1,fy) as the reference's v%1 path (proof: floor(-0.5)=-1 wraps
    // to 1023 == direct 1023, fy=0.5 both) -> no floor needed.
    float v = phi * 0.3183098861837907f;         // /pi

    // atan2(z/egg, nx/egg) == atan2(z, nx): egg > 0 inside the disc
    float theta = fatan2_pos(z, nx);
    float u = theta * 0.15915494309189535f + 0.5f;   // /(2pi); in [0.5,1.0]

    // bilinear setup (wrap); u/v floors dropped (see above)
    float yy = v * (float)TEXW - 0.5f;
    float yf = floorf(yy);
    float fy = yy - yf;
    float gy = 1.0f - fy;
    int y0 = (int)yf & (TEXW - 1);
    int y1 = (y0 + 1) & (TEXW - 1);
    float xx = u * (float)TEXW - 0.5f;
    float xf = floorf(xx);
    float fx = xx - xf;
    float gx = 1.0f - fx;
    int x0 = (int)xf & (TEXW - 1);
    int x1 = (x0 + 1) & (TEXW - 1);
    float w00 = gx * gy, w01 = fx * gy, w10 = gx * fy, w11 = fx * fy;
    int o00 = (y0 * TEXW + x0) * 3;
    int o01 = (y0 * TEXW + x1) * 3;
    int o10 = (y1 * TEXW + x0) * 3;
    int o11 = (y1 * TEXW + x1) * 3;

    F3 a00 = *(const F3*)(tex + o00);
    F3 a01 = *(const F3*)(tex + o01);
    F3 a10 = *(const F3*)(tex + o10);
    F3 a11 = *(const F3*)(tex + o11);
    F3 n00 = *(const F3*)(nmap + o00);
    F3 n01 = *(const F3*)(nmap + o01);
    F3 n10 = *(const F3*)(nmap + o10);
    F3 n11 = *(const F3*)(nmap + o11);

    float ar = a00.x*w00 + a01.x*w01 + a10.x*w10 + a11.x*w11;
    float ag = a00.y*w00 + a01.y*w01 + a10.y*w10 + a11.y*w11;
    float ab = a00.z*w00 + a01.z*w01 + a10.z*w10 + a11.z*w11;
    float tnx = (n00.x*w00 + n01.x*w01 + n10.x*w10 + n11.x*w11) * 2.0f - 1.0f;
    float tny = (n00.y*w00 + n01.y*w01 + n10.y*w10 + n11.y*w11) * 2.0f - 1.0f;
    float tnz = (n00.z*w00 + n01.z*w01 + n10.z*w10 + n11.z*w11) * 2.0f - 1.0f;

    // analytical egg normal (|sn|^2 >= 0.5625 inside the disc)
    float snx = nx * egg, sny = ny, snz = z * egg;
    float sl2 = snx*snx + sny*sny + snz*snz;
    float isl = __builtin_amdgcn_rsqf(sl2);
    float bnx = snx * isl, bny = sny * isl, bnz = snz * isl;

    // TBN closed form (verified == reference Gram-Schmidt + cross):
    // common (ref=up):   t=(-bny*bnx*iq, q, -bny*bnz*iq), b=(-bnz*iq, 0, bnx*iq)
    // use_right (ref=x): t=(q, -bnx*bny*iq, -bnx*bnz*iq), b=(0, bnz*iq, -bny*iq)
    // where q2 = (other-horiz)^2 + bnz^2, iq = rsq(q2), q = q2*iq.
    bool use_right = fabsf(bny) > 0.99f;
    float d = use_right ? bnx : bny;             // dot(ref, n)
    float m = use_right ? bny : bnx;
    float q2 = m * m + bnz * bnz;                // >= 0.0199 in used branch
    float iq = __builtin_amdgcn_rsqf(q2);
    float q  = q2 * iq;
    float e  = -(d * iq);
    float tz = bnz * e;                          // same both branches
    float txc = bnx * e;
    float tyr = bny * e;
    float tx = use_right ? q   : txc;
    float ty = use_right ? tyr : q;
    float bnxiq = bnx * iq, bnyiq = bny * iq, bnziq = bnz * iq;
    float bx = use_right ? 0.0f   : -bnziq;
    float by = use_right ? bnziq  : 0.0f;
    float bz = use_right ? -bnyiq : bnxiq;

    // perturbed normal; BUMP_STRENGTH = 1 -> nrm = normalize(world_n)
    float wx = tnx * tx + tny * bx + tnz * bnx;
    float wy = tnx * ty + tny * by + tnz * bny;
    float wz = tnx * tz + tny * bz + tnz * bnz;
    float wl2 = wx*wx + wy*wy + wz*wz;
    float iwl = __builtin_amdgcn_rsqf(fmaxf(wl2, 1e-12f));
    wx *= iwl; wy *= iwl; wz *= iwl;

    // lighting constants (compile-time folded, f32 semantics)
    float Lx = 0.5f, Ly = 0.7f, Lz = 1.0f;
    float ll = sqrtf(Lx * Lx + Ly * Ly + Lz * Lz);
    Lx /= ll; Ly /= ll; Lz /= ll;
    float Hx = Lx, Hy = Ly, Hz = Lz + 1.0f;
    float hl = sqrtf(Hx * Hx + Hy * Hy + Hz * Hz);
    Hx /= hl; Hy /= hl; Hz /= hl;

    float ndotl = fmaxf(wx * Lx + wy * Ly + wz * Lz, 0.0f);
    float ndoth = fmaxf(wx * Hx + wy * Hy + wz * Hz, 0.0f);
    float s2 = ndoth * ndoth, s4 = s2 * s2, s8 = s4 * s4, s16 = s8 * s8;
    float spec = s16 * s16;                   // ndoth^32
    float ndotv = fmaxf(wz, 0.0f);
    float t1 = 1.0f - ndotv;
    float t2 = t1 * t1, t4 = t2 * t2;
    float fres = 0.04f + 0.96f * (t4 * t1);   // Schlick, F0=0.04
    float ka = 0.1f + ndotl;
    float add = spec * fres;

    // 3 adjacent dword stores -> dwordx3; wave covers 768B contiguous burst
    o[0] = fminf(fmaxf(__builtin_fmaf(ar, ka, add), 0.0f), 1.0f);
    o[1] = fminf(fmaxf(__builtin_fmaf(ag, ka, add), 0.0f), 1.0f);
    o[2] = fminf(fmaxf(__builtin_fmaf(ab, ka, add), 0.0f), 1.0f);
}

extern "C" void kernel_launch(void* const* d_in, const int* in_sizes, int n_in,
                              void* d_out, int out_size, void* d_ws, size_t ws_size,
                              hipStream_t stream) {
    const float* tex  = (const float*)d_in[0];
    const float* nmap = (const float*)d_in[1];
    float* out = (float*)d_out;
    int total = RESN * RESN;                      // 1 px/thread
    dim3 grid(total / 256), block(256);           // 16384 blocks
    hipLaunchKernelGGL(egg_render, grid, block, 0, stream, tex, nmap, out);
}

// Round 11
// 26.318 us; speedup vs baseline: 3.5788x; 1.0810x over previous
//
#include <hip/hip_runtime.h>
#include <math.h>

#define RESN 2048
#define TEXW 1024

// atan2 for y >= 0, returns [0, pi]. Cephes-style: min/max ratio + pi/8
// reduction + 4-term odd minimax + 1 Newton step on rcp. Peak err ~2e-7 rad.
__device__ __forceinline__ float fatan2_pos(float y, float x) {
    float ax = fabsf(x);
    float mn = fminf(ax, y);
    float mx = fmaxf(ax, y);
    float r0 = __builtin_amdgcn_rcpf(mx);
    r0 = r0 * __builtin_fmaf(-mx, r0, 2.0f);        // 1 Newton step -> ~0.5 ulp
    float a = mn * r0;                               // in [0,1]
    bool red = a > 0.41421356f;
    float t = (a - 1.0f) * __builtin_amdgcn_rcpf(a + 1.0f);
    float w = red ? t : a;                           // |w| <= 0.41421356
    float s = w * w;
    float p = __builtin_fmaf(s, 8.05374449538e-2f, -1.38776856032e-1f);
    p = __builtin_fmaf(s, p, 1.99777106478e-1f);
    p = __builtin_fmaf(s, p, -3.33329491539e-1f);
    float r = __builtin_fmaf(w * s, p, w);           // atan(w)
    r = red ? r + 0.78539816339f : r;                // + pi/4
    r = (y > ax) ? 1.57079632679f - r : r;
    r = (x < 0.0f) ? 3.14159265359f - r : r;
    return r;
}

// 12-byte texel -> global_load_dwordx3
struct __align__(4) F3 { float x, y, z; };

__global__ __launch_bounds__(256) void egg_render(
    const float* __restrict__ tex,
    const float* __restrict__ nmap,
    float* __restrict__ out)
{
    // 2 px/thread (same row, 64 apart), FLAT named scalars only -> no
    // scratch (R7's failure was Px structs spilling under a 64-VGPR cap).
    // No min-wave bound: let VGPR ~100, 4-5 waves/SIMD x 128 px/thread.
    // Program order guarantees B's 8 gathers are in flight during A's
    // shade (A-blend waits vmcnt(8), not 0) -> compute/memory overlap.
    int t = blockIdx.x * 256 + threadIdx.x;          // 2,097,152 threads
    int j = t >> 10;                                  // row
    int tr = t & 1023;
    int iA = ((tr >> 6) << 7) + (tr & 63);            // first half of 128-px segment
    int iB = iA + 64;                                 // second half
    float* oA = out + ((size_t)j * RESN + iA) * 3u;
    float* oB = oA + 192u;

    const float invres = 1.0f / (float)RESN;
    // bit-exact vs numpy on the inside-test path: no fma contraction,
    // true IEEE division by 0.85
    float ny = __fmul_rn(__fsub_rn(0.5f, __fmul_rn((float)j, invres)), 2.0f) / 0.85f;
    float nysq = __fmul_rn(ny, ny);

    if (!(nysq <= 1.0f)) {                            // whole row outside
        oA[0] = 0.f; oA[1] = 0.f; oA[2] = 0.f;
        oB[0] = 0.f; oB[1] = 0.f; oB[2] = 0.f;
        return;
    }

    // ---- row-shared (ny-only) ----
    float egg = 1.0f - 0.25f * ny;                    // in [0.75, 1.25]
    float sphi = sqrtf(fmaxf(__builtin_fmaf(-ny, ny, 1.0f), 0.0f));
    float phi = fatan2_pos(sphi, ny);                 // == acos(ny)
    float v = phi * 0.3183098861837907f;              // /pi, in [0,1]; floor provably unneeded
    float yy = v * (float)TEXW - 0.5f;
    float yf = floorf(yy);
    float fy = yy - yf;
    float gy = 1.0f - fy;
    int y0 = (int)yf & (TEXW - 1);
    int y1 = (y0 + 1) & (TEXW - 1);
    int rb0 = y0 * TEXW;
    int rb1 = y1 * TEXW;

    // ---- pixel A: address math ----
    float nxA = __fmul_rn(__fsub_rn(__fmul_rn((float)iA, invres), 0.5f), 2.0f) / 0.85f;
    float rsqA = __fadd_rn(__fmul_rn(nxA, nxA), nysq);
    bool inA = (rsqA <= 1.0f);
    float zA = sqrtf(fmaxf(__fsub_rn(1.0f, rsqA), 0.0f));   // 0 for outside lanes
    float thetaA = fatan2_pos(zA, nxA);                      // outside: {0,pi} -> valid uniform addr
    float uA = thetaA * 0.15915494309189535f + 0.5f;         // in [0.5,1.0]
    float xxA = uA * (float)TEXW - 0.5f;
    float xfA = floorf(xxA);
    float fxA = xxA - xfA;
    float gxA = 1.0f - fxA;
    int x0A = (int)xfA & (TEXW - 1);
    int x1A = (x0A + 1) & (TEXW - 1);
    float w00A = gxA * gy, w01A = fxA * gy, w10A = gxA * fy, w11A = fxA * fy;
    int o00A = (rb0 + x0A) * 3, o01A = (rb0 + x1A) * 3;
    int o10A = (rb1 + x0A) * 3, o11A = (rb1 + x1A) * 3;

    // ---- pixel B: address math ----
    float nxB = __fmul_rn(__fsub_rn(__fmul_rn((float)iB, invres), 0.5f), 2.0f) / 0.85f;
    float rsqB = __fadd_rn(__fmul_rn(nxB, nxB), nysq);
    bool inB = (rsqB <= 1.0f);
    float zB = sqrtf(fmaxf(__fsub_rn(1.0f, rsqB), 0.0f));
    float thetaB = fatan2_pos(zB, nxB);
    float uB = thetaB * 0.15915494309189535f + 0.5f;
    float xxB = uB * (float)TEXW - 0.5f;
    float xfB = floorf(xxB);
    float fxB = xxB - xfB;
    float gxB = 1.0f - fxB;
    int x0B = (int)xfB & (TEXW - 1);
    int x1B = (x0B + 1) & (TEXW - 1);
    float w00B = gxB * gy, w01B = fxB * gy, w10B = gxB * fy, w11B = fxB * fy;
    int o00B = (rb0 + x0B) * 3, o01B = (rb0 + x1B) * 3;
    int o10B = (rb1 + x0B) * 3, o11B = (rb1 + x1B) * 3;

    // wave-uniform skip when every lane of both halves is outside
    if (!(__any((int)inA) || __any((int)inB))) {
        oA[0] = 0.f; oA[1] = 0.f; oA[2] = 0.f;
        oB[0] = 0.f; oB[1] = 0.f; oB[2] = 0.f;
        return;
    }

    // ---- issue all 16 gathers back-to-back ----
    F3 aA00 = *(const F3*)(tex + o00A);
    F3 aA01 = *(const F3*)(tex + o01A);
    F3 aA10 = *(const F3*)(tex + o10A);
    F3 aA11 = *(const F3*)(tex + o11A);
    F3 nA00 = *(const F3*)(nmap + o00A);
    F3 nA01 = *(const F3*)(nmap + o01A);
    F3 nA10 = *(const F3*)(nmap + o10A);
    F3 nA11 = *(const F3*)(nmap + o11A);
    F3 aB00 = *(const F3*)(tex + o00B);
    F3 aB01 = *(const F3*)(tex + o01B);
    F3 aB10 = *(const F3*)(tex + o10B);
    F3 aB11 = *(const F3*)(tex + o11B);
    F3 nB00 = *(const F3*)(nmap + o00B);
    F3 nB01 = *(const F3*)(nmap + o01B);
    F3 nB10 = *(const F3*)(nmap + o10B);
    F3 nB11 = *(const F3*)(nmap + o11B);

    // lighting constants (compile-time folded, f32 semantics)
    float Lx = 0.5f, Ly = 0.7f, Lz = 1.0f;
    float ll = sqrtf(Lx * Lx + Ly * Ly + Lz * Lz);
    Lx /= ll; Ly /= ll; Lz /= ll;
    float Hx = Lx, Hy = Ly, Hz = Lz + 1.0f;
    float hl = sqrtf(Hx * Hx + Hy * Hy + Hz * Hz);
    Hx /= hl; Hy /= hl; Hz /= hl;

    // ---- shade A (waits only on A's 8 loads; B's stay in flight) ----
    {
        float ar = aA00.x*w00A + aA01.x*w01A + aA10.x*w10A + aA11.x*w11A;
        float ag = aA00.y*w00A + aA01.y*w01A + aA10.y*w10A + aA11.y*w11A;
        float ab = aA00.z*w00A + aA01.z*w01A + aA10.z*w10A + aA11.z*w11A;
        float tnx = (nA00.x*w00A + nA01.x*w01A + nA10.x*w10A + nA11.x*w11A) * 2.0f - 1.0f;
        float tny = (nA00.y*w00A + nA01.y*w01A + nA10.y*w10A + nA11.y*w11A) * 2.0f - 1.0f;
        float tnz = (nA00.z*w00A + nA01.z*w01A + nA10.z*w10A + nA11.z*w11A) * 2.0f - 1.0f;

        float snx = nxA * egg, sny = ny, snz = zA * egg;
        float sl2 = snx*snx + sny*sny + snz*snz;       // > 0.5 even for outside lanes
        float isl = __builtin_amdgcn_rsqf(sl2);
        float bnx = snx * isl, bny = sny * isl, bnz = snz * isl;

        bool use_right = fabsf(bny) > 0.99f;
        float d = use_right ? bnx : bny;
        float m = use_right ? bny : bnx;
        float q2 = m * m + bnz * bnz;
        float iq = __builtin_amdgcn_rsqf(q2);
        float q  = q2 * iq;
        float e  = -(d * iq);
        float tzv = bnz * e;
        float tx = use_right ? q : (bnx * e);
        float ty = use_right ? (bny * e) : q;
        float bnxiq = bnx * iq, bnyiq = bny * iq, bnziq = bnz * iq;
        float bx = use_right ? 0.0f   : -bnziq;
        float by = use_right ? bnziq  : 0.0f;
        float bz = use_right ? -bnyiq : bnxiq;

        float wx = tnx * tx + tny * bx + tnz * bnx;
        float wy = tnx * ty + tny * by + tnz * bny;
        float wz = tnx * tzv + tny * bz + tnz * bnz;
        float wl2 = wx*wx + wy*wy + wz*wz;
        float iwl = __builtin_amdgcn_rsqf(fmaxf(wl2, 1e-12f));
        wx *= iwl; wy *= iwl; wz *= iwl;

        float ndotl = fmaxf(wx * Lx + wy * Ly + wz * Lz, 0.0f);
        float ndoth = fmaxf(wx * Hx + wy * Hy + wz * Hz, 0.0f);
        float s2 = ndoth * ndoth, s4 = s2 * s2, s8 = s4 * s4, s16 = s8 * s8;
        float spec = s16 * s16;
        float ndotv = fmaxf(wz, 0.0f);
        float t1 = 1.0f - ndotv;
        float t2 = t1 * t1, t4 = t2 * t2;
        float fres = 0.04f + 0.96f * (t4 * t1);
        float ka = 0.1f + ndotl;
        float add = spec * fres;

        oA[0] = inA ? fminf(fmaxf(__builtin_fmaf(ar, ka, add), 0.0f), 1.0f) : 0.0f;
        oA[1] = inA ? fminf(fmaxf(__builtin_fmaf(ag, ka, add), 0.0f), 1.0f) : 0.0f;
        oA[2] = inA ? fminf(fmaxf(__builtin_fmaf(ab, ka, add), 0.0f), 1.0f) : 0.0f;
    }

    // ---- shade B ----
    {
        float ar = aB00.x*w00B + aB01.x*w01B + aB10.x*w10B + aB11.x*w11B;
        float ag = aB00.y*w00B + aB01.y*w01B + aB10.y*w10B + aB11.y*w11B;
        float ab = aB00.z*w00B + aB01.z*w01B + aB10.z*w10B + aB11.z*w11B;
        float tnx = (nB00.x*w00B + nB01.x*w01B + nB10.x*w10B + nB11.x*w11B) * 2.0f - 1.0f;
        float tny = (nB00.y*w00B + nB01.y*w01B + nB10.y*w10B + nB11.y*w11B) * 2.0f - 1.0f;
        float tnz = (nB00.z*w00B + nB01.z*w01B + nB10.z*w10B + nB11.z*w11B) * 2.0f - 1.0f;

        float snx = nxB * egg, sny = ny, snz = zB * egg;
        float sl2 = snx*snx + sny*sny + snz*snz;
        float isl = __builtin_amdgcn_rsqf(sl2);
        float bnx = snx * isl, bny = sny * isl, bnz = snz * isl;

        bool use_right = fabsf(bny) > 0.99f;
        float d = use_right ? bnx : bny;
        float m = use_right ? bny : bnx;
        float q2 = m * m + bnz * bnz;
        float iq = __builtin_amdgcn_rsqf(q2);
        float q  = q2 * iq;
        float e  = -(d * iq);
        float tzv = bnz * e;
        float tx = use_right ? q : (bnx * e);
        float ty = use_right ? (bny * e) : q;
        float bnxiq = bnx * iq, bnyiq = bny * iq, bnziq = bnz * iq;
        float bx = use_right ? 0.0f   : -bnziq;
        float by = use_right ? bnziq  : 0.0f;
        float bz = use_right ? -bnyiq : bnxiq;

        float wx = tnx * tx + tny * bx + tnz * bnx;
        float wy = tnx * ty + tny * by + tnz * bny;
        float wz = tnx * tzv + tny * bz + tnz * bnz;
        float wl2 = wx*wx + wy*wy + wz*wz;
        float iwl = __builtin_amdgcn_rsqf(fmaxf(wl2, 1e-12f));
        wx *= iwl; wy *= iwl; wz *= iwl;

        float ndotl = fmaxf(wx * Lx + wy * Ly + wz * Lz, 0.0f);
        float ndoth = fmaxf(wx * Hx + wy * Hy + wz * Hz, 0.0f);
        float s2 = ndoth * ndoth, s4 = s2 * s2, s8 = s4 * s4, s16 = s8 * s8;
        float spec = s16 * s16;
        float ndotv = fmaxf(wz, 0.0f);
        float t1 = 1.0f - ndotv;
        float t2 = t1 * t1, t4 = t2 * t2;
        float fres = 0.04f + 0.96f * (t4 * t1);
        float ka = 0.1f + ndotl;
        float add = spec * fres;

        oB[0] = inB ? fminf(fmaxf(__builtin_fmaf(ar, ka, add), 0.0f), 1.0f) : 0.0f;
        oB[1] = inB ? fminf(fmaxf(__builtin_fmaf(ag, ka, add), 0.0f), 1.0f) : 0.0f;
        oB[2] = inB ? fminf(fmaxf(__builtin_fmaf(ab, ka, add), 0.0f), 1.0f) : 0.0f;
    }
}

extern "C" void kernel_launch(void* const* d_in, const int* in_sizes, int n_in,
                              void* d_out, int out_size, void* d_ws, size_t ws_size,
                              hipStream_t stream) {
    const float* tex  = (const float*)d_in[0];
    const float* nmap = (const float*)d_in[1];
    float* out = (float*)d_out;
    int total_threads = RESN * RESN / 2;          // 2,097,152
    dim3 grid(total_threads / 256), block(256);   // 8192 blocks
    hipLaunchKernelGGL(egg_render, grid, block, 0, stream, tex, nmap, out);
}